// Round 2
// baseline (436.650 us; speedup 1.0000x reference)
//
#include <hip/hip_runtime.h>
#include <stdint.h>

typedef __attribute__((ext_vector_type(8))) short short8;
typedef __attribute__((ext_vector_type(4))) float f32x4;
typedef __attribute__((ext_vector_type(2))) float f32x2;

#define RES 56
#define NCH 256
#define HD 32
#define SW 392     // valid tokens per window (56*7)
#define SP 416     // padded tokens (26*16 = 13*32)

// LDS layout (bytes), total 64768 (<64KB -> 2 blocks/CU)
#define KB_OFF   0        // K bf16 [tok(416)][hd(32)]  pitch 32 shorts
#define VT_OFF   26624    // V^T bf16 [d(32)][tok(416)] pitch 416 shorts, col-swizzled
#define WB_OFF   53248    // conv w [9][32] f32
#define BB_OFF   54400    // bias [32] f32
#define PB_OFF   54528    // per-wave 2560 B: P chunk dbuf (2x1024) / lepe scratch [32][18] f32
#define SMEM_SZ  64768

__device__ __forceinline__ short f2bf(float f) {           // RNE f32->bf16
    uint32_t u = __float_as_uint(f);
    u = u + 0x7fffu + ((u >> 16) & 1u);
    return (short)(u >> 16);
}
__device__ __forceinline__ float bf2f(short s) {
    return __uint_as_float(((uint32_t)(uint16_t)s) << 16);
}

__global__ __launch_bounds__(256, 2) void lepe_attn_kernel(
    const float* __restrict__ qg, const float* __restrict__ kg,
    const float* __restrict__ vg, const float* __restrict__ wg,
    const float* __restrict__ bg, float* __restrict__ outg)
{
    __shared__ __align__(16) char smem[SMEM_SZ];
    short* kbuf = (short*)(smem + KB_OFF);
    short* vtb  = (short*)(smem + VT_OFF);
    float* wbuf = (float*)(smem + WB_OFF);
    float* bbuf = (float*)(smem + BB_OFF);

    const int tid  = threadIdx.x;
    const int lane = tid & 63;
    const int wv   = tid >> 6;
    const int col  = lane & 15;   // MFMA n/m index
    const int g    = lane >> 4;   // MFMA quad

    const int h  = blockIdx.x & 7;        // head
    const int bw = blockIdx.x >> 3;       // window id
    const int s  = bw & 7;                // stripe index
    const int b  = bw >> 3;               // batch

    const int cb = h * HD;                // channel base
    const int tb = b * (RES * RES);       // token base

    // ---- stage conv weights + bias (288 + 32 items from 256 threads) ----
    for (int i = tid; i < 288; i += 256)
        wbuf[i] = wg[(i >> 5) * NCH + cb + (i & 31)];
    if (tid < 32)
        bbuf[tid] = bg[cb + tid];

    // ---- stage K (plain) and V (transposed, col-swizzled) as bf16 ----
    #pragma unroll
    for (int p0 = 0; p0 < 1792; p0 += 256) {
        int idx = p0 + tid;
        if (idx < 1664) {                       // 416 toks * 4 hd-groups
            int tok = idx >> 2;
            int hd8 = (idx & 3) << 3;
            f32x4 ka = {0.f,0.f,0.f,0.f}, kb2 = ka, va = ka, vb = ka;
            if (tok < SW) {
                int y  = (tok * 9363) >> 16;    // tok/7 exact for tok<1871
                int xx = tok - y * 7;
                int n  = y * RES + s * 7 + xx;
                int off = (tb + n) * NCH + cb + hd8;
                ka  = *(const f32x4*)(kg + off);
                kb2 = *(const f32x4*)(kg + off + 4);
                va  = *(const f32x4*)(vg + off);
                vb  = *(const f32x4*)(vg + off + 4);
            }
            short8 ks;
            ks[0]=f2bf(ka[0]);  ks[1]=f2bf(ka[1]);  ks[2]=f2bf(ka[2]);  ks[3]=f2bf(ka[3]);
            ks[4]=f2bf(kb2[0]); ks[5]=f2bf(kb2[1]); ks[6]=f2bf(kb2[2]); ks[7]=f2bf(kb2[3]);
            *(short8*)(kbuf + tok * 32 + hd8) = ks;   // 16B-aligned ds_write_b128
            short8 vs;
            vs[0]=f2bf(va[0]); vs[1]=f2bf(va[1]); vs[2]=f2bf(va[2]); vs[3]=f2bf(va[3]);
            vs[4]=f2bf(vb[0]); vs[5]=f2bf(vb[1]); vs[6]=f2bf(vb[2]); vs[7]=f2bf(vb[3]);
            // V^T with column swizzle tok' = tok ^ (d & 24); here d = hd8+j so d&24 == hd8
            int tswz = tok ^ hd8;
            #pragma unroll
            for (int j = 0; j < 8; ++j)
                vtb[(hd8 + j) * SP + tswz] = vs[j];
        }
    }
    __syncthreads();

    const float SCL = 0.17677669529663688f * 1.4426950408889634f; // hd^-0.5 * log2(e)
    const f32x4 zero4 = {0.f, 0.f, 0.f, 0.f};
    const float NINF = -__builtin_inff();

    for (int qt = wv; qt < 25; qt += 4) {
        // ---- Q B-fragment from global (lane: q = col, hd = 8g..8g+7) ----
        int qrow = (qt << 4) + col;
        int tq = qrow < SW ? qrow : SW - 1;
        int yq = (tq * 9363) >> 16;
        int nq = yq * RES + s * 7 + (tq - yq * 7);
        short8 qf;
        {
            int qoff = (tb + nq) * NCH + cb + (g << 3);
            f32x4 qa = *(const f32x4*)(qg + qoff);
            f32x4 qb = *(const f32x4*)(qg + qoff + 4);
            qf[0]=f2bf(qa[0]*SCL); qf[1]=f2bf(qa[1]*SCL); qf[2]=f2bf(qa[2]*SCL); qf[3]=f2bf(qa[3]*SCL);
            qf[4]=f2bf(qb[0]*SCL); qf[5]=f2bf(qb[1]*SCL); qf[6]=f2bf(qb[2]*SCL); qf[7]=f2bf(qb[3]*SCL);
        }

        // ---- S^T = K * Q^T : lane holds S^T[tok=kt*16+4g+r][q=col] ----
        f32x4 Sf[26];
        #pragma unroll
        for (int kt = 0; kt < 25; ++kt) {
            short8 kf = *(const short8*)(kbuf + (kt * 16 + col) * 32 + (g << 3));
            Sf[kt] = __builtin_amdgcn_mfma_f32_16x16x32_bf16(kf, qf, zero4, 0, 0, 0);
        }
        #pragma unroll
        for (int r = 0; r < 4; ++r) Sf[24][r] = (g >= 2) ? NINF : Sf[24][r]; // toks 392..399
        Sf[25] = (f32x4){NINF, NINF, NINF, NINF};                            // toks 400..415

        // ---- softmax over tok (fixed q per lane) ----
        float m = NINF;
        #pragma unroll
        for (int kt = 0; kt < 25; ++kt) {
            #pragma unroll
            for (int r = 0; r < 4; ++r) m = fmaxf(m, Sf[kt][r]);
        }
        m = fmaxf(m, __shfl_xor(m, 16));
        m = fmaxf(m, __shfl_xor(m, 32));

        uint32_t pk[26][2];
        float l = 0.f;
        #pragma unroll
        for (int kt = 0; kt < 26; ++kt) {
            float p0 = exp2f(Sf[kt][0] - m);
            float p1 = exp2f(Sf[kt][1] - m);
            float p2 = exp2f(Sf[kt][2] - m);
            float p3 = exp2f(Sf[kt][3] - m);
            // truncate-pack pairs to bf16 (v_perm), sum the truncated values for consistency
            uint32_t u01 = __builtin_amdgcn_perm(__float_as_uint(p1), __float_as_uint(p0), 0x07060302u);
            uint32_t u23 = __builtin_amdgcn_perm(__float_as_uint(p3), __float_as_uint(p2), 0x07060302u);
            pk[kt][0] = u01; pk[kt][1] = u23;
            l += __uint_as_float(u01 << 16) + __uint_as_float(u01 & 0xffff0000u)
               + __uint_as_float(u23 << 16) + __uint_as_float(u23 & 0xffff0000u);
        }
        l += __shfl_xor(l, 16);
        l += __shfl_xor(l, 32);
        float invl = 1.0f / l;

        // ---- O^T = V^T * P^T over 13 chunks of 32 tokens ----
        f32x4 O0 = zero4, O1 = zero4;
        short* pb = (short*)(smem + PB_OFF + wv * 2560);
        const int dlo = col, dhi = col + 16;
        const int vsl = (g << 3) ^ (dlo & 24);
        const int vsh = (g << 3) ^ (dhi & 24);
        #pragma unroll
        for (int c = 0; c < 13; ++c) {
            short* pbc = pb + (c & 1) * 512;
            // write P[q=col][tok_in_chunk]: 4 consecutive toks per b64
            *(uint2*)(pbc + col * 32 +      (g << 2)) = make_uint2(pk[2*c][0],   pk[2*c][1]);
            *(uint2*)(pbc + col * 32 + 16 + (g << 2)) = make_uint2(pk[2*c+1][0], pk[2*c+1][1]);
            short8 bf = *(const short8*)(pbc + col * 32 + (g << 3));
            short8 a0 = *(const short8*)(vtb + dlo * SP + c * 32 + vsl);
            short8 a1 = *(const short8*)(vtb + dhi * SP + c * 32 + vsh);
            O0 = __builtin_amdgcn_mfma_f32_16x16x32_bf16(a0, bf, O0, 0, 0, 0);
            O1 = __builtin_amdgcn_mfma_f32_16x16x32_bf16(a1, bf, O1, 0, 0, 0);
        }

        // ---- LePE for this tile's 16 tokens, via V^T in LDS ----
        float* scr = (float*)(smem + PB_OFF + wv * 2560);   // reuse P region (free now)
        {
            int d = lane >> 1, half = lane & 1;
            int t0 = (qt << 4) + (half << 3);
            int dsw = d & 24;
            const short* vrow = vtb + d * SP;
            float vals[24];
            #pragma unroll
            for (int kk = 0; kk < 3; ++kk) {
                int t8 = t0 - 8 + (kk << 3);
                if (t8 < 0) t8 = 0;                          // garbage but always masked
                short8 bv = *(const short8*)(vrow + (t8 ^ dsw));
                #pragma unroll
                for (int j = 0; j < 8; ++j) vals[kk * 8 + j] = bf2f(bv[j]);
            }
            float wr[9];
            #pragma unroll
            for (int t9 = 0; t9 < 9; ++t9) wr[t9] = wbuf[t9 * 32 + d];
            float bs = bbuf[d];
            float o[8];
            #pragma unroll
            for (int i = 0; i < 8; ++i) {
                int t = t0 + i;
                int yy = (t * 9363) >> 16;
                int xxi = t - yy * 7;
                float mlft = (xxi == 0) ? 0.f : 1.f;
                float mrgt = (xxi == 6) ? 0.f : 1.f;
                float mu   = (t >= 7)   ? 1.f : 0.f;
                float md   = (t <= 384) ? 1.f : 0.f;
                float top = wr[0]*(vals[i]*mlft)    + wr[1]*vals[i+1]  + wr[2]*(vals[i+2]*mrgt);
                float mid = wr[3]*(vals[i+7]*mlft)  + wr[4]*vals[i+8]  + wr[5]*(vals[i+9]*mrgt);
                float bot = wr[6]*(vals[i+14]*mlft) + wr[7]*vals[i+15] + wr[8]*(vals[i+16]*mrgt);
                o[i] = bs + mid + mu * top + md * bot;
            }
            #pragma unroll
            for (int mm = 0; mm < 4; ++mm) {
                f32x2 pr = {o[2*mm], o[2*mm+1]};
                *(f32x2*)(scr + d * 18 + (half << 3) + 2 * mm) = pr;  // pitch 18 f32
            }
        }

        // ---- normalize, add LePE, store ----
        f32x4 r0, r1;
        #pragma unroll
        for (int r = 0; r < 4; ++r) {
            r0[r] = O0[r] * invl + scr[(4 * g + r) * 18 + col];
            r1[r] = O1[r] * invl + scr[(16 + 4 * g + r) * 18 + col];
        }
        if (qrow < SW) {
            float* op = outg + (tb + nq) * NCH + cb + (g << 2);
            *(f32x4*)op = r0;
            *(f32x4*)(op + 16) = r1;
        }
    }
}

extern "C" void kernel_launch(void* const* d_in, const int* in_sizes, int n_in,
                              void* d_out, int out_size, void* d_ws, size_t ws_size,
                              hipStream_t stream) {
    const float* q  = (const float*)d_in[0];
    const float* k  = (const float*)d_in[1];
    const float* v  = (const float*)d_in[2];
    const float* wc = (const float*)d_in[3];
    const float* bc = (const float*)d_in[4];
    float* out = (float*)d_out;
    hipLaunchKernelGGL(lepe_attn_kernel, dim3(2048), dim3(256), 0, stream,
                       q, k, v, wc, bc, out);
}